// Round 5
// baseline (36765.024 us; speedup 1.0000x reference)
//
#include <hip/hip_runtime.h>

// ELMo 2-layer LSTM-with-projection, persistent kernel for MI355X (gfx950).
// B=32, T=1024, H=512(=input), CELL=4096, gates=16384, K(fused)=1024.
//
// R7: LATENCY-CHAIN SURGERY. R6 (32.4ms, 31.6us/step) is serialized-MALL-
// round-trip bound (MfmaUtil 3%): ~11 round trips/step. This round removes
// ~5 without changing ANY arithmetic bit vs R6 (c-trajectory is a 1024-step
// clipped integrator; R5 proved reduction-order changes fail final_c):
//  - reduce: load all 32 partials as bf16x4 (2 batches of 16 ull) THEN the
//    identical ascending-w2 per-(n,pi) f32 add chain (was 4 batches of 8
//    scalar u16 loads). 4x fewer load instrs, 2 wide round trips.
//  - x(t+1) prefetched into registers INSIDE the bar2 window (between
//    arrival and poll, so loads fly during the barrier). L1's seal(t+1)
//    wait moves into the same window; the top-of-step wait is gone.
//  - both h halves' sc1 loads issue once at step top (dumped per half from
//    regs): 2 serialized h round trips -> 1.
//  - L1's residual f32 read prefetched at step top.
//
// Fenceless coherence (R4-R6): no release/acquire fences (they cost full
// L2 wb + L1/L2 inv per barrier). All cross-WG data (P, hbuf, out row t,
// counters) via relaxed agent-scope atomics = global sc0 sc1 (MALL-direct).
// Release = __syncthreads' vmcnt(0) drain before the arrival add. Barrier
// arrivals spread over 8 sub-counters (256B apart, 16 each); lanes 0..7
// poll. Grid: WGs 0..127 = layer 1, 128..255 = layer 2 (pipelined); 512
// thr/WG, full batch N=32, both layers' [Wi;Ws] bf16 in VGPRs.

#define TT 1024
#define HH 512
#define CC 4096

typedef __bf16 bf16_t;
typedef __attribute__((ext_vector_type(8))) __bf16 bf16x8;
typedef __attribute__((ext_vector_type(4))) __bf16 bf16x4;
typedef __attribute__((ext_vector_type(4))) float f32x4;
typedef unsigned long long ull_t;

#define OUT_FH 16777216u          // 32*1024*512
#define OUT_FC 16809984u          // + 2*32*512

__device__ __forceinline__ float fsigm(float x) { return 1.0f / (1.0f + __expf(-x)); }
__device__ __forceinline__ float ftanh(float x) {
  x = fminf(fmaxf(x, -15.f), 15.f);
  float e = __expf(2.f * x);
  return (e - 1.f) / (e + 1.f);
}

// Device-coherent (MALL) accessors: relaxed agent atomics -> sc0 sc1, no fences.
__device__ __forceinline__ void st_ull(void* p, ull_t v) {
  __hip_atomic_store((ull_t*)p, v, __ATOMIC_RELAXED, __HIP_MEMORY_SCOPE_AGENT);
}
__device__ __forceinline__ ull_t ld_ull(const void* p) {
  return __hip_atomic_load((const ull_t*)p, __ATOMIC_RELAXED, __HIP_MEMORY_SCOPE_AGENT);
}
__device__ __forceinline__ void st_f32(float* p, float v) {
  __hip_atomic_store(p, v, __ATOMIC_RELAXED, __HIP_MEMORY_SCOPE_AGENT);
}
__device__ __forceinline__ float ld_f32(const float* p) {
  return __hip_atomic_load(p, __ATOMIC_RELAXED, __HIP_MEMORY_SCOPE_AGENT);
}
__device__ __forceinline__ void st_u16(void* p, unsigned short v) {
  __hip_atomic_store((unsigned short*)p, v, __ATOMIC_RELAXED, __HIP_MEMORY_SCOPE_AGENT);
}

// Fenceless grid barrier over one layer-group (128 WGs).
__device__ __forceinline__ void gridbar(unsigned* base, int wgi, unsigned bark) {
  __syncthreads();
  if (threadIdx.x == 0)
    __hip_atomic_fetch_add(base + (wgi & 7) * 64, 1u, __ATOMIC_RELAXED,
                           __HIP_MEMORY_SCOPE_AGENT);
  if (threadIdx.x < 8) {
    const unsigned tgt = 16u * bark;
    while (__hip_atomic_load(base + threadIdx.x * 64, __ATOMIC_RELAXED,
                             __HIP_MEMORY_SCOPE_AGENT) < tgt)
      __builtin_amdgcn_s_sleep(1);
  }
  __syncthreads();
}

__global__ void prep(const int* __restrict__ mask, int* __restrict__ len,
                     unsigned* __restrict__ cnt) {
  const int b = blockIdx.x, tid = threadIdx.x;
  if (b == 0)
    for (int i = tid; i < 1024; i += 256)
      __hip_atomic_store(cnt + i, 0u, __ATOMIC_RELAXED, __HIP_MEMORY_SCOPE_AGENT);
  int s = 0;
  for (int i = tid; i < TT; i += 256) s += mask[b * TT + i];
  __shared__ int r[256];
  r[tid] = s; __syncthreads();
  for (int st = 128; st > 0; st >>= 1) {
    if (tid < st) r[tid] += r[tid + st];
    __syncthreads();
  }
  if (tid == 0) len[b] = r[0];
}

__global__ __launch_bounds__(512, 2) void elmo_lstm(
    const float* __restrict__ xin,
    const float* __restrict__ Wi_g, const float* __restrict__ Ws_g,
    const float* __restrict__ bs_g, const float* __restrict__ Wp_g,
    float* __restrict__ out,
    unsigned* __restrict__ cnt, const int* __restrict__ len_g,
    bf16_t* __restrict__ P, bf16_t* __restrict__ hbuf) {
  const int g    = blockIdx.x;
  const int L    = g >> 7;        // layer (0: WGs 0..127, 1: WGs 128..255)
  const int wgi  = g & 127;
  const int cb   = wgi * 32;      // owned cell base
  const int tid  = threadIdx.x;
  const int wv   = tid >> 6;      // wave 0..7
  const int gate = wv >> 1;       // 0..3
  const int mt   = wv & 1;        // M-tile within gate (16 rows each)
  const int lane = tid & 63;
  const int lm   = lane & 15;
  const int lq   = lane >> 4;
  const int pb   = wgi * 4;       // owned h-column base (reduce phase)
  const int sr   = tid & 15;      // staging row (n within half)
  const int sq   = tid >> 4;      // staging col group; <16 = x, >=16 = h

  // xh[16][1032] bf16 (33,024B) union rbuf[32][4][4] f32 (2,048B).
  __shared__ __align__(16) char uA[33024];
  __shared__ float  gbuf[4][32][33];   // [gate][cell][n]
  __shared__ float  cbuf[32][33];      // persistent c-state [cell][n]
  __shared__ bf16_t abuf[32][48];      // act [n][cell]
  __shared__ int    lenl[32];

  bf16_t (*xh)[1032]   = (bf16_t(*)[1032])uA;
  float  (*rbuf)[4][4] = (float(*)[4][4])uA;   // [n][pi][s]

  if (tid < 32) lenl[tid] = len_g[tid];

  unsigned* myc = cnt + L * 512;       // own group's 8 sub-counters
  unsigned* c1  = cnt;                 // layer-1 group's sub-counters

  const float* WiL = Wi_g + (size_t)L * CC * 4 * HH;
  const float* WsL = Ws_g + (size_t)L * CC * 4 * HH;
  const float* bsL = bs_g + (size_t)L * CC * 4;
  const float* WpL = Wp_g + (size_t)L * HH * CC;

  // ---- weights -> registers: gate A-fragments (16 rows x 1024 K per wave)
  bf16x8 wfrag[32];                    // 128 VGPRs
  {
    const int row = gate * CC + cb + mt * 16 + lm;
#pragma unroll
    for (int ks = 0; ks < 32; ++ks) {
      const int k = ks * 32 + lq * 8;
      const float* src = (k < HH) ? (WiL + (size_t)row * HH + k)
                                  : (WsL + (size_t)row * HH + (k - HH));
      float4 a = ((const float4*)src)[0];
      float4 b = ((const float4*)src)[1];
      bf16x8 f;
      f[0] = (bf16_t)a.x; f[1] = (bf16_t)a.y; f[2] = (bf16_t)a.z; f[3] = (bf16_t)a.w;
      f[4] = (bf16_t)b.x; f[5] = (bf16_t)b.y; f[6] = (bf16_t)b.z; f[7] = (bf16_t)b.w;
      wfrag[ks] = f;
    }
  }
  float biasv[4];
#pragma unroll
  for (int r = 0; r < 4; ++r)
    biasv[r] = bsL[gate * CC + cb + mt * 16 + lq * 4 + r];

  bf16x8 pfrag[4];                     // Wp rows wv*64+pt*16+lm, cols cb+lq*8
#pragma unroll
  for (int pt = 0; pt < 4; ++pt) {
    const float* src = WpL + (size_t)(wv * 64 + pt * 16 + lm) * CC + cb + lq * 8;
    float4 a = ((const float4*)src)[0];
    float4 b = ((const float4*)src)[1];
    bf16x8 f;
    f[0] = (bf16_t)a.x; f[1] = (bf16_t)a.y; f[2] = (bf16_t)a.z; f[3] = (bf16_t)a.w;
    f[4] = (bf16_t)b.x; f[5] = (bf16_t)b.y; f[6] = (bf16_t)b.z; f[7] = (bf16_t)b.w;
    pfrag[pt] = f;
  }

  // ---- state init ----
  for (int i = tid; i < 32 * 33; i += 512) (&cbuf[0][0])[i] = 0.f;
  bf16_t* hb = hbuf + (size_t)L * 32 * HH;
  if (tid < 128) {
    int n = tid >> 2, p = pb + (tid & 3);
    st_u16(hb + (size_t)n * HH + p, 0);
  }
  unsigned bark = 0;
  gridbar(myc, wgi, ++bark);

  bf16_t* Pl = P + (size_t)L * 128 * 32 * HH;    // own layer's partial buffer
  float hp = 0.f;                                // running h (tid<128 only)
  bf16x4 xp[16];                                 // prefetched x slices (sq<16)

  // x(t) prefetch: sq<16 threads hold x[n=sr][co..co+32] (xp[0..7]) and
  // x[n=16+sr][co..co+32] (xp[8..15]) as bf16, bit-identical converts to R6.
  auto prefetch_x = [&](int tn) {
    if (sq < 16) {
      const int co = sq * 32;
      if (L == 0) {
        const float* x0 = xin + ((size_t)sr * TT + tn) * HH + co;
        const float* x1 = xin + ((size_t)(16 + sr) * TT + tn) * HH + co;
#pragma unroll
        for (int i = 0; i < 8; ++i) {
          float4 v = ((const float4*)x0)[i];
          bf16x4 pv = { (bf16_t)v.x, (bf16_t)v.y, (bf16_t)v.z, (bf16_t)v.w };
          xp[i] = pv;
        }
#pragma unroll
        for (int i = 0; i < 8; ++i) {
          float4 v = ((const float4*)x1)[i];
          bf16x4 pv = { (bf16_t)v.x, (bf16_t)v.y, (bf16_t)v.z, (bf16_t)v.w };
          xp[8 + i] = pv;
        }
      } else {
        const ull_t* x0 = (const ull_t*)(out + ((size_t)sr * TT + tn) * HH + co);
        const ull_t* x1 = (const ull_t*)(out + ((size_t)(16 + sr) * TT + tn) * HH + co);
#pragma unroll
        for (int i = 0; i < 8; ++i) {
          float2 a = __builtin_bit_cast(float2, ld_ull(x0 + 2 * i));
          float2 b = __builtin_bit_cast(float2, ld_ull(x0 + 2 * i + 1));
          bf16x4 pv = { (bf16_t)a.x, (bf16_t)a.y, (bf16_t)b.x, (bf16_t)b.y };
          xp[i] = pv;
        }
#pragma unroll
        for (int i = 0; i < 8; ++i) {
          float2 a = __builtin_bit_cast(float2, ld_ull(x1 + 2 * i));
          float2 b = __builtin_bit_cast(float2, ld_ull(x1 + 2 * i + 1));
          bf16x4 pv = { (bf16_t)a.x, (bf16_t)a.y, (bf16_t)b.x, (bf16_t)b.y };
          xp[8 + i] = pv;
        }
      }
    }
  };

  // prologue: x(0) (L1 first waits for L0 seal(0) = bark 3)
  if (L == 1) {
    if (tid < 8) {
      while (__hip_atomic_load(c1 + tid * 64, __ATOMIC_RELAXED,
                               __HIP_MEMORY_SCOPE_AGENT) < 16u * 3u)
        __builtin_amdgcn_s_sleep(1);
    }
    __syncthreads();
  }
  prefetch_x(0);

#pragma unroll 1
  for (int t = 0; t < TT; ++t) {
    // ---- issue both h halves + L1 residual up front ----
    ull_t h0v[8], h1v[8];
    if (sq >= 16) {
      const int co = (sq - 16) * 32;
#pragma unroll
      for (int i = 0; i < 8; ++i)
        h0v[i] = ld_ull(hb + (size_t)sr * HH + co + i * 4);
#pragma unroll
      for (int i = 0; i < 8; ++i)
        h1v[i] = ld_ull(hb + (size_t)(16 + sr) * HH + co + i * 4);
    }
    float resv = 0.f;
    if (L == 1 && tid < 128)
      resv = ld_f32(out + ((size_t)(tid >> 2) * TT + t) * HH + pb + (tid & 3));

    // ---- gate GEMM over two N=16 halves through one xh buffer ----
    f32x4 acc0, acc1;
#pragma unroll
    for (int nh = 0; nh < 2; ++nh) {
      if (sq < 16) {                       // x from prefetch regs
        const int co = sq * 32;
#pragma unroll
        for (int i = 0; i < 8; ++i)
          *(bf16x4*)&xh[sr][co + i * 4] = xp[nh * 8 + i];
      } else {                             // h from regs (loads issued above)
        const int co = (sq - 16) * 32;
        if (nh == 0) {
#pragma unroll
          for (int i = 0; i < 8; ++i)
            *(ull_t*)&xh[sr][HH + co + i * 4] = h0v[i];
        } else {
#pragma unroll
          for (int i = 0; i < 8; ++i)
            *(ull_t*)&xh[sr][HH + co + i * 4] = h1v[i];
        }
      }
      __syncthreads();
      f32x4 a = { biasv[0], biasv[1], biasv[2], biasv[3] };
#pragma unroll
      for (int ks = 0; ks < 32; ++ks) {
        bf16x8 bfr = *(const bf16x8*)&xh[lm][ks * 32 + lq * 8];
        a = __builtin_amdgcn_mfma_f32_16x16x32_bf16(wfrag[ks], bfr, a, 0, 0, 0);
      }
      if (nh == 0) acc0 = a; else acc1 = a;
      __syncthreads();                     // xh reads done before re-stage
    }

    // ---- gates -> LDS ----
    {
      const int crow = mt * 16;
#pragma unroll
      for (int r = 0; r < 4; ++r) {
        gbuf[gate][crow + lq * 4 + r][lm]      = acc0[r];
        gbuf[gate][crow + lq * 4 + r][16 + lm] = acc1[r];
      }
    }
    __syncthreads();

    // ---- elementwise LSTM cell (2 (cell,n) pairs / thread) ----
#pragma unroll
    for (int e = 0; e < 2; ++e) {
      const int pp = tid * 2 + e;
      const int cell = pp >> 5, n = pp & 31;
      float ig = gbuf[0][cell][n], fg = gbuf[1][cell][n];
      float mg = gbuf[2][cell][n], og = gbuf[3][cell][n];
      float iv = fsigm(ig), fv = fsigm(fg), gv = ftanh(mg), ov = fsigm(og);
      float cp = cbuf[cell][n];
      float c  = fminf(fmaxf(iv * gv + fv * cp, -3.f), 3.f);
      const bool valid = t < lenl[n];
      float cn = valid ? c : cp;
      cbuf[cell][n] = cn;
      abuf[n][cell] = (bf16_t)(ov * ftanh(c));
      if (t == lenl[n] - 1)
        st_f32(out + OUT_FC + ((size_t)(L * 32 + n)) * CC + cb + cell, cn);
    }
    __syncthreads();

    // ---- projection over own 32 cells: MALL stores, [wg][n][p] ----
    {
      bf16x8 b0 = *(const bf16x8*)&abuf[lm][lq * 8];
      bf16x8 b1 = *(const bf16x8*)&abuf[16 + lm][lq * 8];
#pragma unroll
      for (int pt = 0; pt < 4; ++pt) {
        f32x4 p0 = { 0.f, 0.f, 0.f, 0.f };
        f32x4 p1 = { 0.f, 0.f, 0.f, 0.f };
        p0 = __builtin_amdgcn_mfma_f32_16x16x32_bf16(pfrag[pt], b0, p0, 0, 0, 0);
        p1 = __builtin_amdgcn_mfma_f32_16x16x32_bf16(pfrag[pt], b1, p1, 0, 0, 0);
        const int prow = wv * 64 + pt * 16 + lq * 4;
        bf16x4 s0 = { (bf16_t)p0[0], (bf16_t)p0[1], (bf16_t)p0[2], (bf16_t)p0[3] };
        bf16x4 s1 = { (bf16_t)p1[0], (bf16_t)p1[1], (bf16_t)p1[2], (bf16_t)p1[3] };
        st_ull(&Pl[((size_t)(wgi * 32 + lm)      * HH) + prow],
               __builtin_bit_cast(ull_t, s0));
        st_ull(&Pl[((size_t)(wgi * 32 + 16 + lm) * HH) + prow],
               __builtin_bit_cast(ull_t, s1));
      }
    }
    gridbar(myc, wgi, ++bark);

    // ---- reduce: loads vectorized (bf16x4, 2 batches of 16), add chain
    //      BIT-IDENTICAL to R6: per (n,pi,s) ascending w2, ((r0+r1)+r2)+r3 ----
    if (tid < 128) {
      const int n = tid >> 2, s = tid & 3;
      const bf16_t* Pb = Pl + ((size_t)(s * 32 * 32 + n)) * HH + pb;
      f32x4 sum = { 0.f, 0.f, 0.f, 0.f };
      ull_t v[16];
#pragma unroll
      for (int j = 0; j < 16; ++j) v[j] = ld_ull(Pb + (size_t)j * 32 * HH);
#pragma unroll
      for (int j = 0; j < 16; ++j) {
        bf16x4 b = __builtin_bit_cast(bf16x4, v[j]);
        sum[0] += (float)b[0]; sum[1] += (float)b[1];
        sum[2] += (float)b[2]; sum[3] += (float)b[3];
      }
#pragma unroll
      for (int j = 0; j < 16; ++j) v[j] = ld_ull(Pb + (size_t)(16 + j) * 32 * HH);
#pragma unroll
      for (int j = 0; j < 16; ++j) {
        bf16x4 b = __builtin_bit_cast(bf16x4, v[j]);
        sum[0] += (float)b[0]; sum[1] += (float)b[1];
        sum[2] += (float)b[2]; sum[3] += (float)b[3];
      }
      rbuf[n][0][s] = sum[0]; rbuf[n][1][s] = sum[1];
      rbuf[n][2][s] = sum[2]; rbuf[n][3][s] = sum[3];
    }
    __syncthreads();
    if (tid < 128) {
      const int n = tid >> 2, pi = tid & 3, p = pb + pi;
      float h = rbuf[n][pi][0] + rbuf[n][pi][1] + rbuf[n][pi][2] + rbuf[n][pi][3];
      h = fminf(fmaxf(h, -3.f), 3.f);
      const bool valid = t < lenl[n];
      float hn = valid ? h : hp;
      union { bf16_t b; unsigned short u; } hu; hu.b = (bf16_t)hn;
      st_u16(hb + (size_t)n * HH + p, hu.u);
      float outv = valid ? h : 0.f;
      size_t oi = ((size_t)n * TT + t) * HH + p;
      if (L == 0) st_f32(out + oi, outv);   // seal row t at MALL for layer 2
      else        out[oi] = resv + outv;    // residual (resv prefetched at top)
      if (t == lenl[n] - 1)
        st_f32(out + OUT_FH + ((size_t)(L * 32 + n)) * HH + p, hn);
      hp = hn;
    }

    // ---- bar2 with embedded x(t+1) prefetch (loads fly during the poll) ----
    {
      const unsigned bk = ++bark;
      __syncthreads();                     // drain h/out sc1 stores
      if (tid == 0)
        __hip_atomic_fetch_add(myc + (wgi & 7) * 64, 1u, __ATOMIC_RELAXED,
                               __HIP_MEMORY_SCOPE_AGENT);
      const bool pf = (t + 1 < TT);
      if (pf && L == 1) {                  // wait for L0 seal(t+1), then safe
        if (tid < 8) {
          const unsigned tgt = 16u * (2u * (unsigned)(t + 1) + 3u);
          while (__hip_atomic_load(c1 + tid * 64, __ATOMIC_RELAXED,
                                   __HIP_MEMORY_SCOPE_AGENT) < tgt)
            __builtin_amdgcn_s_sleep(1);
        }
        __syncthreads();
      }
      if (pf) prefetch_x(t + 1);
      if (tid < 8) {
        const unsigned tgt = 16u * bk;
        while (__hip_atomic_load(myc + tid * 64, __ATOMIC_RELAXED,
                                 __HIP_MEMORY_SCOPE_AGENT) < tgt)
          __builtin_amdgcn_s_sleep(1);
      }
      __syncthreads();
    }
  }
}

extern "C" void kernel_launch(void* const* d_in, const int* in_sizes, int n_in,
                              void* d_out, int out_size, void* d_ws, size_t ws_size,
                              hipStream_t stream) {
  const float* xin = (const float*)d_in[0];
  const int*   mask = (const int*)d_in[1];
  const float* Wi  = (const float*)d_in[2];
  const float* Ws  = (const float*)d_in[3];
  const float* bs  = (const float*)d_in[4];
  const float* Wp  = (const float*)d_in[5];
  float* out = (float*)d_out;
  char* ws = (char*)d_ws;

  unsigned* cnt = (unsigned*)ws;                 // 2 groups x 8 subcnt x 256B = 4KB
  int* len      = (int*)(ws + 4096);
  bf16_t* P    = (bf16_t*)(ws + 8192);           // 2*128*32*512 bf16 = 8 MB
  bf16_t* hbuf = (bf16_t*)(ws + 8192 + (size_t)2 * 128 * 32 * 512 * 2);

  prep<<<32, 256, 0, stream>>>(mask, len, cnt);
  elmo_lstm<<<256, 512, 0, stream>>>(xin, Wi, Ws, bs, Wp, out, cnt, len, P, hbuf);
}